// Round 1
// baseline (38445.874 us; speedup 1.0000x reference)
//
#include <hip/hip_runtime.h>
#include <math.h>

#define TPB 256

namespace {

constexpr int B_ = 2, T_ = 1024, D_ = 1024, H_ = 16, L_ = 12, V_ = 50257;
constexpr int DFF_ = 2730, CAP_ = 128, M_ = 2048;  // M_ = B*T tokens

// ---------------- embedding: x = embed[ids] + pos ----------------
__global__ __launch_bounds__(TPB) void k_embed(const int* __restrict__ ids,
    const float* __restrict__ emb, const float* __restrict__ pos,
    float* __restrict__ X) {
  int row = blockIdx.x;            // b*T + t
  int t = row % T_;
  size_t id = (size_t)ids[row];
  const float* e = emb + id * (size_t)D_;
  const float* p = pos + (size_t)t * D_;
  float* x = X + (size_t)row * D_;
  for (int d = threadIdx.x; d < D_; d += TPB) x[d] = e[d] + p[d];
}

// ---------------- RMSNorm (eps 1e-6) ----------------
__global__ __launch_bounds__(TPB) void k_rms(const float* __restrict__ X,
    const float* __restrict__ w, float* __restrict__ out) {
  int row = blockIdx.x;
  const float* x = X + (size_t)row * D_;
  float ss = 0.f;
  for (int d = threadIdx.x; d < D_; d += TPB) { float v = x[d]; ss += v * v; }
  __shared__ float red[TPB];
  red[threadIdx.x] = ss; __syncthreads();
  for (int off = TPB / 2; off > 0; off >>= 1) {
    if (threadIdx.x < off) red[threadIdx.x] += red[threadIdx.x + off];
    __syncthreads();
  }
  float scale = 1.0f / sqrtf(red[0] / (float)D_ + 1e-6f);
  float* o = out + (size_t)row * D_;
  for (int d = threadIdx.x; d < D_; d += TPB) o[d] = x[d] * scale * w[d];
}

// ---------------- general NT GEMM: C[M,N] = A[M,K] @ B[N,K]^T (+R) -------
// A row-major lda, B row-major ldb (K contiguous in both), C/R stride ldc.
__global__ __launch_bounds__(TPB) void k_gemm(const float* __restrict__ A, int lda,
    const float* __restrict__ B, int ldb, float* C, int ldc, const float* R,
    int M, int N, int K) {
  __shared__ float As[16][65];
  __shared__ float Bs[16][65];
  int tid = threadIdx.x;
  int tx = tid & 15, ty = tid >> 4;
  int m0 = blockIdx.y * 64, n0 = blockIdx.x * 64;
  float acc[4][4] = {{0.f}};
  for (int k0 = 0; k0 < K; k0 += 16) {
#pragma unroll
    for (int i = 0; i < 4; ++i) {
      int idx = tid + i * 256;
      int r = idx >> 4, kk = idx & 15;
      int gk = k0 + kk;
      int gm = m0 + r;
      As[kk][r] = (gm < M && gk < K) ? A[(size_t)gm * lda + gk] : 0.f;
      int gn = n0 + r;
      Bs[kk][r] = (gn < N && gk < K) ? B[(size_t)gn * ldb + gk] : 0.f;
    }
    __syncthreads();
#pragma unroll
    for (int kk = 0; kk < 16; ++kk) {
      float a0[4], b0[4];
#pragma unroll
      for (int i = 0; i < 4; ++i) a0[i] = As[kk][ty * 4 + i];
#pragma unroll
      for (int j = 0; j < 4; ++j) b0[j] = Bs[kk][tx * 4 + j];
#pragma unroll
      for (int i = 0; i < 4; ++i)
#pragma unroll
        for (int j = 0; j < 4; ++j) acc[i][j] = fmaf(a0[i], b0[j], acc[i][j]);
    }
    __syncthreads();
  }
#pragma unroll
  for (int i = 0; i < 4; ++i) {
    int gm = m0 + ty * 4 + i;
    if (gm >= M) continue;
#pragma unroll
    for (int j = 0; j < 4; ++j) {
      int gn = n0 + tx * 4 + j;
      if (gn >= N) continue;
      float v = acc[i][j];
      if (R) v += R[(size_t)gm * ldc + gn];
      C[(size_t)gm * ldc + gn] = v;
    }
  }
}

// ---------------- attention: one wave per (q,h,b), online softmax --------
// qkv layout: [b*T + t][3072]  (q @ h*64, k @ 1024+h*64, v @ 2048+h*64)
__global__ __launch_bounds__(64) void k_attn(const float* __restrict__ qkv,
    float* __restrict__ o, int T) {
  int qp = blockIdx.x, h = blockIdx.y, b = blockIdx.z;
  int lane = threadIdx.x;
  const float* base = qkv + (size_t)b * T * 3072;
  float qv = base[(size_t)qp * 3072 + h * 64 + lane] * 0.125f;  // 1/sqrt(64)
  const float* Kp = base + 1024 + h * 64 + lane;
  const float* Vp = base + 2048 + h * 64 + lane;
  float m = -INFINITY, l = 0.f, acc = 0.f;
  for (int k = 0; k <= qp; ++k) {
    float p = qv * Kp[(size_t)k * 3072];
#pragma unroll
    for (int off = 1; off < 64; off <<= 1) p += __shfl_xor(p, off, 64);
    float mn = fmaxf(m, p);
    float eo = expf(m - mn);
    float e = expf(p - mn);
    l = l * eo + e;
    acc = acc * eo + e * Vp[(size_t)k * 3072];
    m = mn;
  }
  o[(size_t)(b * T + qp) * 1024 + h * 64 + lane] = acc / l;
}

// ---------------- row dot: out[row] = X[row,:].v ----------------
__global__ __launch_bounds__(TPB) void k_rowdot(const float* __restrict__ X,
    const float* __restrict__ v, float* __restrict__ out, int D) {
  int row = blockIdx.x;
  const float* x = X + (size_t)row * D;
  float p = 0.f;
  for (int d = threadIdx.x; d < D; d += TPB) p += x[d] * v[d];
  __shared__ float red[TPB];
  red[threadIdx.x] = p; __syncthreads();
  for (int off = TPB / 2; off > 0; off >>= 1) {
    if (threadIdx.x < off) red[threadIdx.x] += red[threadIdx.x + off];
    __syncthreads();
  }
  if (threadIdx.x == 0) out[row] = red[0];
}

// gate scalar: out[row] = sigmoid(dot(X[row], w) + b)
__global__ __launch_bounds__(TPB) void k_rowdot_sig(const float* __restrict__ X,
    const float* __restrict__ w, const float* __restrict__ bias,
    float* __restrict__ out, int D) {
  int row = blockIdx.x;
  const float* x = X + (size_t)row * D;
  float p = 0.f;
  for (int d = threadIdx.x; d < D; d += TPB) p += x[d] * w[d];
  __shared__ float red[TPB];
  red[threadIdx.x] = p; __syncthreads();
  for (int off = TPB / 2; off > 0; off >>= 1) {
    if (threadIdx.x < off) red[threadIdx.x] += red[threadIdx.x + off];
    __syncthreads();
  }
  if (threadIdx.x == 0) {
    float s = red[0] + bias[0];
    out[row] = 1.0f / (1.0f + expf(-s));
  }
}

// ---------------- MoD top-128 per batch (desc order, stable ties) --------
__global__ __launch_bounds__(TPB) void k_topk(const float* __restrict__ scores,
    int* __restrict__ idx_out) {
  int b = blockIdx.x;
  __shared__ float s[T_];
  __shared__ float rv[TPB];
  __shared__ int ri[TPB];
  int tid = threadIdx.x;
  for (int t = tid; t < T_; t += TPB) s[t] = scores[b * T_ + t];
  __syncthreads();
  for (int it = 0; it < CAP_; ++it) {
    float bv = -INFINITY; int bi = -1;
    for (int t = tid; t < T_; t += TPB) {
      float v = s[t];
      if (v > bv) { bv = v; bi = t; }   // increasing t scan keeps lowest tie index
    }
    rv[tid] = bv; ri[tid] = bi;
    __syncthreads();
    for (int off = TPB / 2; off > 0; off >>= 1) {
      if (tid < off) {
        float v2 = rv[tid + off]; int i2 = ri[tid + off];
        if (v2 > rv[tid] || (v2 == rv[tid] && i2 >= 0 && (ri[tid] < 0 || i2 < ri[tid]))) {
          rv[tid] = v2; ri[tid] = i2;
        }
      }
      __syncthreads();
    }
    if (tid == 0) { idx_out[b * CAP_ + it] = ri[0]; s[ri[0]] = -INFINITY; }
    __syncthreads();
  }
}

__global__ __launch_bounds__(TPB) void k_gather(const float* __restrict__ X,
    const int* __restrict__ idx, float* __restrict__ XS) {
  int j = blockIdx.x;                 // 0..B*CAP-1
  int b = j / CAP_, r = j % CAP_;
  int src = b * T_ + idx[b * CAP_ + r];
  const float* xi = X + (size_t)src * D_;
  float* xo = XS + (size_t)j * D_;
  for (int d = threadIdx.x; d < D_; d += TPB) xo[d] = xi[d];
}

__global__ __launch_bounds__(TPB) void k_scatter(float* __restrict__ X,
    const int* __restrict__ idx, const float* __restrict__ XS) {
  int j = blockIdx.x;
  int b = j / CAP_, r = j % CAP_;
  int dst = b * T_ + idx[b * CAP_ + r];
  float* xo = X + (size_t)dst * D_;
  const float* xi = XS + (size_t)j * D_;
  for (int d = threadIdx.x; d < D_; d += TPB) xo[d] = xi[d];
}

// ---------------- kNN memory: top-8 of 128 sims + softmax + weighted sum --
__global__ __launch_bounds__(TPB) void k_mem_retrieve(const float* __restrict__ sim,
    const float* __restrict__ mem_vals, float* __restrict__ out) {
  int row = blockIdx.x;
  __shared__ float sv[128];
  __shared__ float w8[8];
  __shared__ int i8[8];
  int tid = threadIdx.x;
  if (tid < 128) sv[tid] = sim[(size_t)row * 128 + tid] * 0.03125f;  // 1/sqrt(1024)
  __syncthreads();
  if (tid == 0) {
    for (int k = 0; k < 8; ++k) {
      float bv = -INFINITY; int bi = 0;
      for (int t = 0; t < 128; ++t) {
        float v = sv[t];
        if (v > bv) { bv = v; bi = t; }
      }
      w8[k] = bv; i8[k] = bi; sv[bi] = -INFINITY;
    }
    float mx = w8[0];   // descending: first is max
    float sum = 0.f;
    for (int k = 0; k < 8; ++k) { float e = expf(w8[k] - mx); w8[k] = e; sum += e; }
    for (int k = 0; k < 8; ++k) w8[k] /= sum;
  }
  __syncthreads();
  float* o = out + (size_t)row * D_;
  for (int d = tid; d < D_; d += TPB) {
    float acc = 0.f;
#pragma unroll
    for (int k = 0; k < 8; ++k) acc += w8[k] * mem_vals[(size_t)i8[k] * D_ + d];
    o[d] = acc;
  }
}

// ---------------- elementwise ----------------
__global__ __launch_bounds__(TPB) void k_silu_mul(float* __restrict__ h1,
    const float* __restrict__ h2, int total) {
  int i = blockIdx.x * TPB + threadIdx.x;
  if (i < total) {
    float x = h1[i];
    float s = x / (1.0f + expf(-x));
    h1[i] = s * h2[i];
  }
}

// h = gelu_exact(h + bias[col])  (bias nullable)
__global__ __launch_bounds__(TPB) void k_gelu_bias(float* __restrict__ h,
    const float* __restrict__ bias, int total, int N) {
  int i = blockIdx.x * TPB + threadIdx.x;
  if (i < total) {
    float x = h[i];
    if (bias) x += bias[i % N];
    h[i] = 0.5f * x * (1.0f + erff(x * 0.70710678118654752f));
  }
}

__global__ __launch_bounds__(TPB) void k_concat2(const float* __restrict__ A,
    const float* __restrict__ Bv, float* __restrict__ out) {
  int row = blockIdx.x;
  const float* a = A + (size_t)row * D_;
  const float* b = Bv + (size_t)row * D_;
  float* o = out + (size_t)row * 2 * D_;
  for (int d = threadIdx.x; d < D_; d += TPB) { o[d] = a[d]; o[D_ + d] = b[d]; }
}

__global__ __launch_bounds__(TPB) void k_add_gated(float* __restrict__ X,
    const float* __restrict__ gate, const float* __restrict__ R) {
  int row = blockIdx.x;
  float g = gate[row];
  float* x = X + (size_t)row * D_;
  const float* r = R + (size_t)row * D_;
  for (int d = threadIdx.x; d < D_; d += TPB) x[d] += g * r[d];
}

}  // namespace

extern "C" void kernel_launch(void* const* d_in, const int* in_sizes, int n_in,
                              void* d_out, int out_size, void* d_ws, size_t ws_size,
                              hipStream_t stream) {
  const int*   ids      = (const int*)  d_in[0];
  const float* embed    = (const float*)d_in[1];
  const float* pos      = (const float*)d_in[2];
  const float* n1       = (const float*)d_in[3];
  const float* qkv_w    = (const float*)d_in[4];
  const float* out_w    = (const float*)d_in[5];
  const float* n2       = (const float*)d_in[6];
  const float* w1       = (const float*)d_in[7];
  const float* w2       = (const float*)d_in[8];
  const float* w3       = (const float*)d_in[9];
  const float* router   = (const float*)d_in[10];
  const float* mem_keys = (const float*)d_in[11];
  const float* mem_vals = (const float*)d_in[12];
  const float* mem_q    = (const float*)d_in[13];
  const float* mem_out  = (const float*)d_in[14];
  const float* gate_w1  = (const float*)d_in[15];
  const float* gate_b1  = (const float*)d_in[16];
  const float* gate_w2  = (const float*)d_in[17];
  const float* gate_b2  = (const float*)d_in[18];
  const float* lat_norm = (const float*)d_in[19];
  const float* lat_w1   = (const float*)d_in[20];
  const float* lat_w2   = (const float*)d_in[21];
  const float* fin_norm = (const float*)d_in[22];
  const float* lm_head  = (const float*)d_in[23];
  float* OUT = (float*)d_out;

  // workspace layout (floats); total ~110 MB
  float* X    = (float*)d_ws;                         // 2048*1024
  float* XN   = X    + (size_t)M_ * D_;               // 2048*1024
  float* QKV  = XN   + (size_t)M_ * D_;               // 2048*3072 (also gate-concat & latent hidden)
  float* ATTO = QKV  + (size_t)M_ * 3 * D_;           // 2048*1024 (also retrieved_raw)
  float* H1   = ATTO + (size_t)M_ * D_;               // 2048*2730
  float* H2   = H1   + (size_t)M_ * DFF_;             // 2048*2730
  float* RET  = H2   + (size_t)M_ * DFF_;             // 2048*1024
  float* GH   = RET  + (size_t)M_ * D_;               // 2048*512
  float* SIM  = GH   + (size_t)M_ * 512;              // 2048*128
  float* GATE = SIM  + (size_t)M_ * 128;              // 2048
  float* SC   = GATE + M_;                            // 2048
  float* XS   = SC   + M_;                            // 256*1024
  int*   IDX  = (int*)(XS + (size_t)B_ * CAP_ * D_);  // 256 ints

  auto gemm = [&](const float* A, int lda, const float* Bm, int ldb, float* C,
                  int ldc, const float* Rr, int M, int N, int K) {
    dim3 g((unsigned)((N + 63) / 64), (unsigned)((M + 63) / 64));
    k_gemm<<<g, TPB, 0, stream>>>(A, lda, Bm, ldb, C, ldc, Rr, M, N, K);
  };

  k_embed<<<M_, TPB, 0, stream>>>(ids, embed, pos, X);

  for (int i = 0; i < L_; ++i) {
    const float* qw  = qkv_w + (size_t)i * 3 * D_ * D_;
    const float* ow  = out_w + (size_t)i * D_ * D_;
    const float* w1i = w1 + (size_t)i * DFF_ * D_;
    const float* w2i = w2 + (size_t)i * DFF_ * D_;
    const float* w3i = w3 + (size_t)i * D_ * DFF_;
    if (i & 1) {
      // ---- Mixture-of-Depths layer: top-128 tokens per batch ----
      k_rowdot<<<M_, TPB, 0, stream>>>(X, router + (size_t)i * D_, SC, D_);
      k_topk<<<B_, TPB, 0, stream>>>(SC, IDX);
      k_gather<<<B_ * CAP_, TPB, 0, stream>>>(X, IDX, XS);
      const int Ms = B_ * CAP_;  // 256
      k_rms<<<Ms, TPB, 0, stream>>>(XS, n1 + (size_t)i * D_, XN);
      gemm(XN, D_, qw, D_, QKV, 3 * D_, nullptr, Ms, 3 * D_, D_);
      k_attn<<<dim3(CAP_, H_, B_), 64, 0, stream>>>(QKV, ATTO, CAP_);
      gemm(ATTO, D_, ow, D_, XS, D_, XS, Ms, D_, D_);       // xs += attn
      k_rms<<<Ms, TPB, 0, stream>>>(XS, n2 + (size_t)i * D_, XN);
      gemm(XN, D_, w1i, D_, H1, DFF_, nullptr, Ms, DFF_, D_);
      gemm(XN, D_, w2i, D_, H2, DFF_, nullptr, Ms, DFF_, D_);
      int tot = Ms * DFF_;
      k_silu_mul<<<(tot + TPB - 1) / TPB, TPB, 0, stream>>>(H1, H2, tot);
      gemm(H1, DFF_, w3i, DFF_, XS, D_, XS, Ms, D_, DFF_);  // xs += ff
      k_scatter<<<B_ * CAP_, TPB, 0, stream>>>(X, IDX, XS);
    } else {
      // ---- dense layer ----
      k_rms<<<M_, TPB, 0, stream>>>(X, n1 + (size_t)i * D_, XN);
      gemm(XN, D_, qw, D_, QKV, 3 * D_, nullptr, M_, 3 * D_, D_);
      k_attn<<<dim3(T_, H_, B_), 64, 0, stream>>>(QKV, ATTO, T_);
      gemm(ATTO, D_, ow, D_, X, D_, X, M_, D_, D_);         // x += attn
      k_rms<<<M_, TPB, 0, stream>>>(X, n2 + (size_t)i * D_, XN);
      gemm(XN, D_, w1i, D_, H1, DFF_, nullptr, M_, DFF_, D_);
      gemm(XN, D_, w2i, D_, H2, DFF_, nullptr, M_, DFF_, D_);
      int tot = M_ * DFF_;
      k_silu_mul<<<(tot + TPB - 1) / TPB, TPB, 0, stream>>>(H1, H2, tot);
      gemm(H1, DFF_, w3i, DFF_, X, D_, X, M_, D_, DFF_);    // x += ff
    }
  }

  // ---- kNN memory retrieval ----
  gemm(X, D_, mem_q, D_, XN, D_, nullptr, M_, D_, D_);          // q = x @ mem_q^T
  gemm(XN, D_, mem_keys, D_, SIM, 128, nullptr, M_, 128, D_);   // sim (scale in retrieve)
  k_mem_retrieve<<<M_, TPB, 0, stream>>>(SIM, mem_vals, ATTO);  // weighted mem_values
  gemm(ATTO, D_, mem_out, D_, RET, D_, nullptr, M_, D_, D_);    // retrieved
  k_concat2<<<M_, TPB, 0, stream>>>(X, RET, QKV);               // g_in = [x, retrieved]
  gemm(QKV, 2 * D_, gate_w1, 2 * D_, GH, 512, nullptr, M_, 512, 2 * D_);
  {
    int tg = M_ * 512;
    k_gelu_bias<<<(tg + TPB - 1) / TPB, TPB, 0, stream>>>(GH, gate_b1, tg, 512);
  }
  k_rowdot_sig<<<M_, TPB, 0, stream>>>(GH, gate_w2, gate_b2, GATE, 512);
  k_add_gated<<<M_, TPB, 0, stream>>>(X, GATE, RET);

  // ---- latent reasoning iterations ----
  for (int it = 0; it < 4; ++it) {
    k_rms<<<M_, TPB, 0, stream>>>(X, lat_norm, XN);
    gemm(XN, D_, lat_w1, D_, QKV, 2 * D_, nullptr, M_, 2 * D_, D_);
    int th = M_ * 2 * D_;
    k_gelu_bias<<<(th + TPB - 1) / TPB, TPB, 0, stream>>>(QKV, nullptr, th, 2 * D_);
    gemm(QKV, 2 * D_, lat_w2, 2 * D_, X, D_, X, M_, D_, 2 * D_);
  }

  // ---- final norm + LM head ----
  k_rms<<<M_, TPB, 0, stream>>>(X, fin_norm, XN);
  gemm(XN, D_, lm_head, D_, OUT, V_, nullptr, M_, V_, D_);
}